// Round 9
// baseline (3271.846 us; speedup 1.0000x reference)
//
#include <hip/hip_runtime.h>
#include <math.h>

typedef unsigned short ushort_t;
typedef unsigned int uint_t;
typedef __attribute__((ext_vector_type(8))) short bf16x8;
typedef __attribute__((ext_vector_type(4))) float f32x4;

#define NTOK 131072          // B*S
#define TM 16                // tokens per block
#define SROW 520             // A row stride bf16: 1040B row (16B-aligned b128), 260dw==4 mod 32 (R3-proven phase)
#define SROW2 260            // dword stride
#define K0P 160              // layer0: [z(2),cond(128)] = 130, padded to 160
#define KHP 512              // hidden: h(512) exactly (te,pos folded into beff)
#define EPS 1e-5f

__device__ __forceinline__ ushort_t f2bf(float f) {
    uint_t x = __float_as_uint(f);
    x += 0x7FFFu + ((x >> 16) & 1u);   // RNE
    return (ushort_t)(x >> 16);
}
__device__ __forceinline__ float bf2f(ushort_t u) {
    return __uint_as_float(((uint_t)u) << 16);
}

// ---- weight prep: Wt[n][k] = W[(k+2)][n] bf16, zero-padded to Kpad (te,pos rows folded into beff) ----
__global__ __launch_bounds__(256) void prep_w(const float* __restrict__ W,
                                              ushort_t* __restrict__ dst,
                                              int Kin, int Kpad) {
    int n = blockIdx.x;            // 0..511
    for (int k = threadIdx.x; k < Kpad; k += 256) {
        float v = (k < Kin) ? W[(k + 2) * 512 + n] : 0.0f;
        dst[n * Kpad + k] = f2bf(v);
    }
}

// beff[L][si][n] = b[n] + te*W[0][n] + pos(si)*W[1][n]
__global__ __launch_bounds__(512) void prep_bias(
    const float* __restrict__ t,
    const float* __restrict__ W0, const float* __restrict__ b0,
    const float* __restrict__ W1, const float* __restrict__ b1,
    const float* __restrict__ W2, const float* __restrict__ b2,
    float* __restrict__ beff)
{
    int L  = blockIdx.x >> 6;
    int si = blockIdx.x & 63;
    const float* W = (L == 0) ? W0 : (L == 1) ? W1 : W2;
    const float* b = (L == 0) ? b0 : (L == 1) ? b1 : b2;
    float te  = t[0];
    float pos = (float)(si + 1) * (1.0f / 64.0f);
    int n = threadIdx.x;
    beff[(L * 64 + si) * 512 + n] = b[n] + te * W[n] + pos * W[512 + n];
}

// One fused layer: 48x512 GEMM (primal + 2 tangents share B), per-si beff bias,
// LN+softplus primal + LN/softplus JVP on tangents, bf16 write-back to A.
template<int KPAD>
__device__ __forceinline__ void do_layer(
    const ushort_t* __restrict__ Wt, const float* __restrict__ beffL,
    const float* __restrict__ gg, const float* __restrict__ bev,
    ushort_t* A_s, float (*sbuf)[16][6], int si0)
{
    const int tid  = threadIdx.x;
    const int w    = tid >> 6;      // wave 0..7
    const int lane = tid & 63;
    const int q    = lane >> 4;     // quad 0..3
    const int c16  = lane & 15;
    const int nb   = w * 64;        // wave's 64-column base

    f32x4 acc[3][4];
#pragma unroll
    for (int m = 0; m < 3; m++)
#pragma unroll
        for (int j = 0; j < 4; j++) acc[m][j] = (f32x4){0.f, 0.f, 0.f, 0.f};

    const int koff = q * 8;
    const ushort_t* bp = Wt + (nb + c16) * KPAD + koff;
    const ushort_t* ap = A_s + c16 * SROW + koff;

    for (int ks = 0; ks < KPAD / 32; ks++) {
        bf16x8 af[3], bf[4];
#pragma unroll
        for (int m = 0; m < 3; m++)
            af[m] = *(const bf16x8*)(ap + m * 16 * SROW + ks * 32);
#pragma unroll
        for (int j = 0; j < 4; j++)
            bf[j] = *(const bf16x8*)(bp + j * 16 * KPAD + ks * 32);
#pragma unroll
        for (int m = 0; m < 3; m++)
#pragma unroll
            for (int j = 0; j < 4; j++)
                acc[m][j] = __builtin_amdgcn_mfma_f32_16x16x32_bf16(af[m], bf[j], acc[m][j], 0, 0, 0);
    }

    // per-token bias (te/pos folded into beff); consumed immediately, minimal live range
#pragma unroll
    for (int r = 0; r < 4; r++) {
        const float* bbase = beffL + (si0 + 4 * q + r) * 512 + nb + c16;
#pragma unroll
        for (int j = 0; j < 4; j++)
            acc[0][j][r] += bbase[16 * j];
    }

    // wave-local LN stats (6 sums per token over this wave's 64 cols)
    float st[4][6];
#pragma unroll
    for (int r = 0; r < 4; r++) {
        float s1 = 0.f, s2 = 0.f, a0 = 0.f, x0 = 0.f, a1 = 0.f, x1 = 0.f;
#pragma unroll
        for (int j = 0; j < 4; j++) {
            float p = acc[0][j][r], u0 = acc[1][j][r], u1 = acc[2][j][r];
            s1 += p; s2 += p * p;
            a0 += u0; x0 += p * u0;
            a1 += u1; x1 += p * u1;
        }
        st[r][0] = s1; st[r][1] = s2; st[r][2] = a0; st[r][3] = x0; st[r][4] = a1; st[r][5] = x1;
    }
#pragma unroll
    for (int d = 1; d <= 8; d <<= 1)
#pragma unroll
        for (int r = 0; r < 4; r++)
#pragma unroll
            for (int s = 0; s < 6; s++) st[r][s] += __shfl_xor(st[r][s], d);
    if (c16 == 0) {
#pragma unroll
        for (int r = 0; r < 4; r++)
#pragma unroll
            for (int s = 0; s < 6; s++) sbuf[w][4 * q + r][s] = st[r][s];
    }
    __syncthreads();

    // one thread per token finalizes LN params; params land in sbuf[0][tok][*] (row-disjoint reuse)
    if (tid < TM) {
        float s[6] = {0.f, 0.f, 0.f, 0.f, 0.f, 0.f};
#pragma unroll
        for (int ww = 0; ww < 8; ww++)
#pragma unroll
            for (int k = 0; k < 6; k++) s[k] += sbuf[ww][tid][k];
        const float inv = 1.0f / 512.0f;
        float mu  = s[0] * inv;
        float var = s[1] * inv - mu * mu;
        float rs  = rsqrtf(var + EPS);
        float dm0 = s[2] * inv, dm1 = s[4] * inv;
        float c0 = rs * (s[3] * inv - mu * dm0);
        float c1 = rs * (s[5] * inv - mu * dm1);
        sbuf[0][tid][0] = mu;  sbuf[0][tid][1] = rs;
        sbuf[0][tid][2] = dm0; sbuf[0][tid][3] = c0;
        sbuf[0][tid][4] = dm1; sbuf[0][tid][5] = c1;
    }
    __syncthreads();

    // epilogue: softplus(LN) + JVP, bf16 write-back
    float gv[4], bvv[4];
#pragma unroll
    for (int j = 0; j < 4; j++) {
        gv[j]  = gg[nb + 16 * j + c16];
        bvv[j] = bev[nb + 16 * j + c16];
    }
#pragma unroll
    for (int r = 0; r < 4; r++) {
        int tok = 4 * q + r;
        float mu  = sbuf[0][tok][0], rs = sbuf[0][tok][1];
        float dm0 = sbuf[0][tok][2], c0 = sbuf[0][tok][3];
        float dm1 = sbuf[0][tok][4], c1 = sbuf[0][tok][5];
#pragma unroll
        for (int j = 0; j < 4; j++) {
            int n = nb + 16 * j + c16;
            float p  = acc[0][j][r], u0 = acc[1][j][r], u1 = acc[2][j][r];
            float xh = (p - mu) * rs;
            float y  = fmaf(xh, gv[j], bvv[j]);
            float e  = __expf(-fabsf(y));
            float rinv = 1.0f / (1.0f + e);
            float sig  = (y >= 0.f) ? rinv : e * rinv;
            float sp   = fmaxf(y, 0.f) + __logf(1.0f + e);
            float grs  = gv[j] * rs;
            float dy0  = grs * (u0 - dm0 - xh * c0);
            float dy1  = grs * (u1 - dm1 - xh * c1);
            A_s[tok * SROW + n]        = f2bf(sp);
            A_s[(16 + tok) * SROW + n] = f2bf(sig * dy0);
            A_s[(32 + tok) * SROW + n] = f2bf(sig * dy1);
        }
    }
    __syncthreads();
}

__global__ __launch_bounds__(512, 6) void ode_mfma(
    const float* __restrict__ t, const float* __restrict__ z, const float* __restrict__ cond,
    const ushort_t* __restrict__ Wt0, const ushort_t* __restrict__ Wt1, const ushort_t* __restrict__ Wt2,
    const float* __restrict__ beff,
    const float* __restrict__ g0, const float* __restrict__ be0,
    const float* __restrict__ g1, const float* __restrict__ be1,
    const float* __restrict__ g2, const float* __restrict__ be2,
    const float* __restrict__ W3, const float* __restrict__ b3,
    float* __restrict__ out)
{
    __shared__ ushort_t A_s[48 * SROW];       // 49920 B; rows 0..15 primal, 16..31 u0, 32..47 u1
    __shared__ float sbuf[8][16][6];          // 3072 B; also hosts LN params after barrier

    const int tid = threadIdx.x;
    const int gm0 = blockIdx.x * TM;
    const int si0 = gm0 & 63;                 // tokens gm0..gm0+15 have si = si0..si0+15
    uint_t* A32 = (uint_t*)A_s;

    // ---- zero phase (only regions not overwritten by fill) ----
    for (int i = tid; i < 32 * 80; i += 512) {        // tangent rows 16..47, dw 0..79 (k 0..159)
        int row = 16 + i / 80, d = i % 80;
        A32[row * SROW2 + d] = 0u;
    }
    if (tid < 16 * 15) {                              // primal pad k 130..159 (dw 65..79)
        int row = tid / 15, d = 65 + tid % 15;
        A32[row * SROW2 + d] = 0u;
    }
    __syncthreads();

    // ---- fill phase: layer0 features [z(2), cond(128)] ----
    const float te = t[0];
    if (tid < TM) {
        int tok = tid, gm = gm0 + tok;
        A32[tok * SROW2 + 0] = (uint_t)f2bf(z[gm * 2 + 0]) | ((uint_t)f2bf(z[gm * 2 + 1]) << 16);
        A_s[(16 + tok) * SROW + 0] = (ushort_t)0x3F80;   // u0 = e_{z0} (k=0)
        A_s[(32 + tok) * SROW + 1] = (ushort_t)0x3F80;   // u1 = e_{z1} (k=1)
    }
    {
        int bi = gm0 >> 6;                               // 16 tokens share one batch row
        for (int i = tid; i < TM * 64; i += 512) {
            int tok = i >> 6, c2 = i & 63;
            const float2 cv = *(const float2*)&cond[bi * 128 + 2 * c2];
            A32[tok * SROW2 + 1 + c2] = (uint_t)f2bf(cv.x) | ((uint_t)f2bf(cv.y) << 16);
        }
    }
    __syncthreads();

    do_layer<K0P>(Wt0, beff + 0 * 64 * 512, g0, be0, A_s, sbuf, si0);
    do_layer<KHP>(Wt1, beff + 1 * 64 * 512, g1, be1, A_s, sbuf, si0);
    do_layer<KHP>(Wt2, beff + 2 * 64 * 512, g2, be2, A_s, sbuf, si0);

    // ---- layer 3: h(512) @ W3[2:,:]; add te/pos terms to primal only ----
    {
        int tok = tid >> 5;       // 0..15
        int l32 = tid & 31;
        int gm  = gm0 + tok;
        const float2* W3v = (const float2*)W3;
        float a0 = 0.f, a1 = 0.f, d0 = 0.f, d1 = 0.f;
        for (int k = l32; k < 512; k += 32) {
            float2 wv = W3v[k + 2];
            float ax  = bf2f(A_s[tok * SROW + k]);
            float au0 = bf2f(A_s[(16 + tok) * SROW + k]);
            float au1 = bf2f(A_s[(32 + tok) * SROW + k]);
            a0 = fmaf(ax, wv.x, a0);
            a1 = fmaf(ax, wv.y, a1);
            d0 = fmaf(au0, wv.x, d0);
            d1 = fmaf(au1, wv.y, d1);
        }
#pragma unroll
        for (int d = 1; d <= 16; d <<= 1) {
            a0 += __shfl_xor(a0, d); a1 += __shfl_xor(a1, d);
            d0 += __shfl_xor(d0, d); d1 += __shfl_xor(d1, d);
        }
        if (l32 == 0) {
            float pos = (float)((gm & 63) + 1) * (1.0f / 64.0f);
            out[gm * 2 + 0]    = a0 + b3[0] + te * W3[0] + pos * W3[2];
            out[gm * 2 + 1]    = a1 + b3[1] + te * W3[1] + pos * W3[3];
            out[NTOK * 2 + gm] = -(d0 + d1);
        }
    }
}

extern "C" void kernel_launch(void* const* d_in, const int* in_sizes, int n_in,
                              void* d_out, int out_size, void* d_ws, size_t ws_size,
                              hipStream_t stream) {
    const float* t    = (const float*)d_in[0];
    const float* z    = (const float*)d_in[1];
    const float* cond = (const float*)d_in[2];
    const float* W0   = (const float*)d_in[3];
    const float* b0   = (const float*)d_in[4];
    const float* g0   = (const float*)d_in[5];
    const float* be0  = (const float*)d_in[6];
    const float* W1   = (const float*)d_in[7];
    const float* b1   = (const float*)d_in[8];
    const float* g1   = (const float*)d_in[9];
    const float* be1  = (const float*)d_in[10];
    const float* W2   = (const float*)d_in[11];
    const float* b2   = (const float*)d_in[12];
    const float* g2   = (const float*)d_in[13];
    const float* be2  = (const float*)d_in[14];
    const float* W3   = (const float*)d_in[15];
    const float* b3   = (const float*)d_in[16];
    float* out = (float*)d_out;

    ushort_t* Wt0 = (ushort_t*)d_ws;                    // 512*160
    ushort_t* Wt1 = Wt0 + 512 * K0P;                    // 512*512
    ushort_t* Wt2 = Wt1 + 512 * KHP;                    // 512*512
    float*    beff = (float*)(Wt2 + 512 * KHP);         // 3*64*512 fp32

    hipLaunchKernelGGL(prep_w, dim3(512), dim3(256), 0, stream, W0, Wt0, 130, K0P);
    hipLaunchKernelGGL(prep_w, dim3(512), dim3(256), 0, stream, W1, Wt1, 512, KHP);
    hipLaunchKernelGGL(prep_w, dim3(512), dim3(256), 0, stream, W2, Wt2, 512, KHP);
    hipLaunchKernelGGL(prep_bias, dim3(192), dim3(512), 0, stream,
                       t, W0, b0, W1, b1, W2, b2, beff);

    hipLaunchKernelGGL(ode_mfma, dim3(NTOK / TM), dim3(512), 0, stream,
                       t, z, cond, Wt0, Wt1, Wt2, beff,
                       g0, be0, g1, be1, g2, be2, W3, b3, out);
}

// Round 10
// 1367.749 us; speedup vs baseline: 2.3921x; 2.3921x over previous
//
#include <hip/hip_runtime.h>
#include <math.h>

typedef unsigned short ushort_t;
typedef unsigned int uint_t;
typedef __attribute__((ext_vector_type(8))) short bf16x8;
typedef __attribute__((ext_vector_type(4))) float f32x4;

#define NTOK 131072          // B*S
#define TM 16                // tokens per block
#define SROW 520             // A row stride bf16: 1040B row (16B-aligned b128), 260dw==4 mod 32 (R3-proven phase)
#define SROW2 260            // dword stride
#define K0P 160              // layer0: [z(2),cond(128)] = 130, padded to 160
#define KHP 512              // hidden: h(512) exactly (te,pos folded into beff)
#define EPS 1e-5f

__device__ __forceinline__ ushort_t f2bf(float f) {
    uint_t x = __float_as_uint(f);
    x += 0x7FFFu + ((x >> 16) & 1u);   // RNE
    return (ushort_t)(x >> 16);
}
__device__ __forceinline__ float bf2f(ushort_t u) {
    return __uint_as_float(((uint_t)u) << 16);
}

// ---- weight prep: Wt[n][k] = W[(k+2)][n] bf16, zero-padded to Kpad (te,pos rows folded into beff) ----
__global__ __launch_bounds__(256) void prep_w(const float* __restrict__ W,
                                              ushort_t* __restrict__ dst,
                                              int Kin, int Kpad) {
    int n = blockIdx.x;            // 0..511
    for (int k = threadIdx.x; k < Kpad; k += 256) {
        float v = (k < Kin) ? W[(k + 2) * 512 + n] : 0.0f;
        dst[n * Kpad + k] = f2bf(v);
    }
}

// beff[L][si][n] = b[n] + te*W[0][n] + pos(si)*W[1][n]
__global__ __launch_bounds__(512) void prep_bias(
    const float* __restrict__ t,
    const float* __restrict__ W0, const float* __restrict__ b0,
    const float* __restrict__ W1, const float* __restrict__ b1,
    const float* __restrict__ W2, const float* __restrict__ b2,
    float* __restrict__ beff)
{
    int L  = blockIdx.x >> 6;
    int si = blockIdx.x & 63;
    const float* W = (L == 0) ? W0 : (L == 1) ? W1 : W2;
    const float* b = (L == 0) ? b0 : (L == 1) ? b1 : b2;
    float te  = t[0];
    float pos = (float)(si + 1) * (1.0f / 64.0f);
    int n = threadIdx.x;
    beff[(L * 64 + si) * 512 + n] = b[n] + te * W[n] + pos * W[512 + n];
}

// One fused layer: 48x512 GEMM (primal + 2 tangents share B), per-si beff bias,
// LN+softplus primal + LN/softplus JVP on tangents, bf16 write-back to A.
template<int KPAD>
__device__ __forceinline__ void do_layer(
    const ushort_t* __restrict__ Wt, const float* __restrict__ beffL,
    const float* __restrict__ gg, const float* __restrict__ bev,
    ushort_t* A_s, float (*sbuf)[16][6], int si0)
{
    const int tid  = threadIdx.x;
    const int w    = tid >> 6;      // wave 0..7
    const int lane = tid & 63;
    const int q    = lane >> 4;     // quad 0..3
    const int c16  = lane & 15;
    const int nb   = w * 64;        // wave's 64-column base

    f32x4 acc[3][4];
#pragma unroll
    for (int m = 0; m < 3; m++)
#pragma unroll
        for (int j = 0; j < 4; j++) acc[m][j] = (f32x4){0.f, 0.f, 0.f, 0.f};

    const int koff = q * 8;
    const ushort_t* bp = Wt + (nb + c16) * KPAD + koff;
    const ushort_t* ap = A_s + c16 * SROW + koff;

    for (int ks = 0; ks < KPAD / 32; ks++) {
        bf16x8 af[3], bf[4];
#pragma unroll
        for (int m = 0; m < 3; m++)
            af[m] = *(const bf16x8*)(ap + m * 16 * SROW + ks * 32);
#pragma unroll
        for (int j = 0; j < 4; j++)
            bf[j] = *(const bf16x8*)(bp + j * 16 * KPAD + ks * 32);
#pragma unroll
        for (int m = 0; m < 3; m++)
#pragma unroll
            for (int j = 0; j < 4; j++)
                acc[m][j] = __builtin_amdgcn_mfma_f32_16x16x32_bf16(af[m], bf[j], acc[m][j], 0, 0, 0);
    }

    // per-token bias (te/pos folded into beff); consumed immediately, minimal live range
#pragma unroll
    for (int r = 0; r < 4; r++) {
        const float* bbase = beffL + (si0 + 4 * q + r) * 512 + nb + c16;
#pragma unroll
        for (int j = 0; j < 4; j++)
            acc[0][j][r] += bbase[16 * j];
    }

    // wave-local LN stats (6 sums per token over this wave's 64 cols)
    float st[4][6];
#pragma unroll
    for (int r = 0; r < 4; r++) {
        float s1 = 0.f, s2 = 0.f, a0 = 0.f, x0 = 0.f, a1 = 0.f, x1 = 0.f;
#pragma unroll
        for (int j = 0; j < 4; j++) {
            float p = acc[0][j][r], u0 = acc[1][j][r], u1 = acc[2][j][r];
            s1 += p; s2 += p * p;
            a0 += u0; x0 += p * u0;
            a1 += u1; x1 += p * u1;
        }
        st[r][0] = s1; st[r][1] = s2; st[r][2] = a0; st[r][3] = x0; st[r][4] = a1; st[r][5] = x1;
    }
#pragma unroll
    for (int d = 1; d <= 8; d <<= 1)
#pragma unroll
        for (int r = 0; r < 4; r++)
#pragma unroll
            for (int s = 0; s < 6; s++) st[r][s] += __shfl_xor(st[r][s], d);
    if (c16 == 0) {
#pragma unroll
        for (int r = 0; r < 4; r++)
#pragma unroll
            for (int s = 0; s < 6; s++) sbuf[w][4 * q + r][s] = st[r][s];
    }
    __syncthreads();

    // one thread per token finalizes LN params; params land in sbuf[0][tok][*] (row-disjoint reuse)
    if (tid < TM) {
        float s[6] = {0.f, 0.f, 0.f, 0.f, 0.f, 0.f};
#pragma unroll
        for (int ww = 0; ww < 8; ww++)
#pragma unroll
            for (int k = 0; k < 6; k++) s[k] += sbuf[ww][tid][k];
        const float inv = 1.0f / 512.0f;
        float mu  = s[0] * inv;
        float var = s[1] * inv - mu * mu;
        float rs  = rsqrtf(var + EPS);
        float dm0 = s[2] * inv, dm1 = s[4] * inv;
        float c0 = rs * (s[3] * inv - mu * dm0);
        float c1 = rs * (s[5] * inv - mu * dm1);
        sbuf[0][tid][0] = mu;  sbuf[0][tid][1] = rs;
        sbuf[0][tid][2] = dm0; sbuf[0][tid][3] = c0;
        sbuf[0][tid][4] = dm1; sbuf[0][tid][5] = c1;
    }
    __syncthreads();

    // epilogue: softplus(LN) + JVP, bf16 write-back
    float gv[4], bvv[4];
#pragma unroll
    for (int j = 0; j < 4; j++) {
        gv[j]  = gg[nb + 16 * j + c16];
        bvv[j] = bev[nb + 16 * j + c16];
    }
#pragma unroll
    for (int r = 0; r < 4; r++) {
        int tok = 4 * q + r;
        float mu  = sbuf[0][tok][0], rs = sbuf[0][tok][1];
        float dm0 = sbuf[0][tok][2], c0 = sbuf[0][tok][3];
        float dm1 = sbuf[0][tok][4], c1 = sbuf[0][tok][5];
#pragma unroll
        for (int j = 0; j < 4; j++) {
            int n = nb + 16 * j + c16;
            float p  = acc[0][j][r], u0 = acc[1][j][r], u1 = acc[2][j][r];
            float xh = (p - mu) * rs;
            float y  = fmaf(xh, gv[j], bvv[j]);
            float e  = __expf(-fabsf(y));
            float rinv = 1.0f / (1.0f + e);
            float sig  = (y >= 0.f) ? rinv : e * rinv;
            float sp   = fmaxf(y, 0.f) + __logf(1.0f + e);
            float grs  = gv[j] * rs;
            float dy0  = grs * (u0 - dm0 - xh * c0);
            float dy1  = grs * (u1 - dm1 - xh * c1);
            A_s[tok * SROW + n]        = f2bf(sp);
            A_s[(16 + tok) * SROW + n] = f2bf(sig * dy0);
            A_s[(32 + tok) * SROW + n] = f2bf(sig * dy1);
        }
    }
    __syncthreads();
}

__global__ __launch_bounds__(512, 4) void ode_mfma(
    const float* __restrict__ t, const float* __restrict__ z, const float* __restrict__ cond,
    const ushort_t* __restrict__ Wt0, const ushort_t* __restrict__ Wt1, const ushort_t* __restrict__ Wt2,
    const float* __restrict__ beff,
    const float* __restrict__ g0, const float* __restrict__ be0,
    const float* __restrict__ g1, const float* __restrict__ be1,
    const float* __restrict__ g2, const float* __restrict__ be2,
    const float* __restrict__ W3, const float* __restrict__ b3,
    float* __restrict__ out)
{
    __shared__ ushort_t A_s[48 * SROW];       // 49920 B; rows 0..15 primal, 16..31 u0, 32..47 u1
    __shared__ float sbuf[8][16][6];          // 3072 B; also hosts LN params after barrier

    const int tid = threadIdx.x;
    const int gm0 = blockIdx.x * TM;
    const int si0 = gm0 & 63;                 // tokens gm0..gm0+15 have si = si0..si0+15
    uint_t* A32 = (uint_t*)A_s;

    // ---- zero phase (only regions not overwritten by fill) ----
    for (int i = tid; i < 32 * 80; i += 512) {        // tangent rows 16..47, dw 0..79 (k 0..159)
        int row = 16 + i / 80, d = i % 80;
        A32[row * SROW2 + d] = 0u;
    }
    if (tid < 16 * 15) {                              // primal pad k 130..159 (dw 65..79)
        int row = tid / 15, d = 65 + tid % 15;
        A32[row * SROW2 + d] = 0u;
    }
    __syncthreads();

    // ---- fill phase: layer0 features [z(2), cond(128)] ----
    const float te = t[0];
    if (tid < TM) {
        int tok = tid, gm = gm0 + tok;
        A32[tok * SROW2 + 0] = (uint_t)f2bf(z[gm * 2 + 0]) | ((uint_t)f2bf(z[gm * 2 + 1]) << 16);
        A_s[(16 + tok) * SROW + 0] = (ushort_t)0x3F80;   // u0 = e_{z0} (k=0)
        A_s[(32 + tok) * SROW + 1] = (ushort_t)0x3F80;   // u1 = e_{z1} (k=1)
    }
    {
        int bi = gm0 >> 6;                               // 16 tokens share one batch row
        for (int i = tid; i < TM * 64; i += 512) {
            int tok = i >> 6, c2 = i & 63;
            const float2 cv = *(const float2*)&cond[bi * 128 + 2 * c2];
            A32[tok * SROW2 + 1 + c2] = (uint_t)f2bf(cv.x) | ((uint_t)f2bf(cv.y) << 16);
        }
    }
    __syncthreads();

    do_layer<K0P>(Wt0, beff + 0 * 64 * 512, g0, be0, A_s, sbuf, si0);
    do_layer<KHP>(Wt1, beff + 1 * 64 * 512, g1, be1, A_s, sbuf, si0);
    do_layer<KHP>(Wt2, beff + 2 * 64 * 512, g2, be2, A_s, sbuf, si0);

    // ---- layer 3: h(512) @ W3[2:,:]; add te/pos terms to primal only ----
    {
        int tok = tid >> 5;       // 0..15
        int l32 = tid & 31;
        int gm  = gm0 + tok;
        const float2* W3v = (const float2*)W3;
        float a0 = 0.f, a1 = 0.f, d0 = 0.f, d1 = 0.f;
        for (int k = l32; k < 512; k += 32) {
            float2 wv = W3v[k + 2];
            float ax  = bf2f(A_s[tok * SROW + k]);
            float au0 = bf2f(A_s[(16 + tok) * SROW + k]);
            float au1 = bf2f(A_s[(32 + tok) * SROW + k]);
            a0 = fmaf(ax, wv.x, a0);
            a1 = fmaf(ax, wv.y, a1);
            d0 = fmaf(au0, wv.x, d0);
            d1 = fmaf(au1, wv.y, d1);
        }
#pragma unroll
        for (int d = 1; d <= 16; d <<= 1) {
            a0 += __shfl_xor(a0, d); a1 += __shfl_xor(a1, d);
            d0 += __shfl_xor(d0, d); d1 += __shfl_xor(d1, d);
        }
        if (l32 == 0) {
            float pos = (float)((gm & 63) + 1) * (1.0f / 64.0f);
            out[gm * 2 + 0]    = a0 + b3[0] + te * W3[0] + pos * W3[2];
            out[gm * 2 + 1]    = a1 + b3[1] + te * W3[1] + pos * W3[3];
            out[NTOK * 2 + gm] = -(d0 + d1);
        }
    }
}

extern "C" void kernel_launch(void* const* d_in, const int* in_sizes, int n_in,
                              void* d_out, int out_size, void* d_ws, size_t ws_size,
                              hipStream_t stream) {
    const float* t    = (const float*)d_in[0];
    const float* z    = (const float*)d_in[1];
    const float* cond = (const float*)d_in[2];
    const float* W0   = (const float*)d_in[3];
    const float* b0   = (const float*)d_in[4];
    const float* g0   = (const float*)d_in[5];
    const float* be0  = (const float*)d_in[6];
    const float* W1   = (const float*)d_in[7];
    const float* b1   = (const float*)d_in[8];
    const float* g1   = (const float*)d_in[9];
    const float* be1  = (const float*)d_in[10];
    const float* W2   = (const float*)d_in[11];
    const float* b2   = (const float*)d_in[12];
    const float* g2   = (const float*)d_in[13];
    const float* be2  = (const float*)d_in[14];
    const float* W3   = (const float*)d_in[15];
    const float* b3   = (const float*)d_in[16];
    float* out = (float*)d_out;

    ushort_t* Wt0 = (ushort_t*)d_ws;                    // 512*160
    ushort_t* Wt1 = Wt0 + 512 * K0P;                    // 512*512
    ushort_t* Wt2 = Wt1 + 512 * KHP;                    // 512*512
    float*    beff = (float*)(Wt2 + 512 * KHP);         // 3*64*512 fp32

    hipLaunchKernelGGL(prep_w, dim3(512), dim3(256), 0, stream, W0, Wt0, 130, K0P);
    hipLaunchKernelGGL(prep_w, dim3(512), dim3(256), 0, stream, W1, Wt1, 512, KHP);
    hipLaunchKernelGGL(prep_w, dim3(512), dim3(256), 0, stream, W2, Wt2, 512, KHP);
    hipLaunchKernelGGL(prep_bias, dim3(192), dim3(512), 0, stream,
                       t, W0, b0, W1, b1, W2, b2, beff);

    hipLaunchKernelGGL(ode_mfma, dim3(NTOK / TM), dim3(512), 0, stream,
                       t, z, cond, Wt0, Wt1, Wt2, beff,
                       g0, be0, g1, be1, g2, be2, W3, b3, out);
}

// Round 11
// 1023.867 us; speedup vs baseline: 3.1956x; 1.3359x over previous
//
#include <hip/hip_runtime.h>
#include <math.h>

typedef unsigned short ushort_t;
typedef unsigned int uint_t;
typedef __attribute__((ext_vector_type(8))) short bf16x8;
typedef __attribute__((ext_vector_type(4))) float f32x4;

#define NTOK 131072          // B*S
#define TM 16                // tokens per block
#define SROW 584             // A row stride bf16; 1168 B row = 16B-aligned b128 (misalign costs ~330us: R6)
#define K0P 160              // layer0 K padded (132 -> 160)
#define KHP 544              // hidden layers K padded (514 -> 544)
#define EPS 1e-5f

__device__ __forceinline__ ushort_t f2bf(float f) {
    uint_t x = __float_as_uint(f);
    x += 0x7FFFu + ((x >> 16) & 1u);   // RNE
    return (ushort_t)(x >> 16);
}
__device__ __forceinline__ float bf2f(ushort_t u) {
    return __uint_as_float(((uint_t)u) << 16);
}

// ---- weight prep: W[K][512] fp32 -> Wt[n][k] bf16, zero-padded to Kpad ----
__global__ __launch_bounds__(256) void prep_w(const float* __restrict__ W,
                                              ushort_t* __restrict__ dst,
                                              int K, int Kpad) {
    int n = blockIdx.x;            // 0..511
    for (int k = threadIdx.x; k < Kpad; k += 256) {
        float v = (k < K) ? W[k * 512 + n] : 0.0f;
        dst[n * Kpad + k] = f2bf(v);
    }
}

// One fused layer: 48x512 GEMM (primal + 2 tangents share B), bias, LN+softplus
// primal + LN/softplus JVP on tangents, bf16 write-back to A.
template<int KPAD>
__device__ __forceinline__ void do_layer(
    const ushort_t* __restrict__ Wt, const float* __restrict__ bb,
    const float* __restrict__ gg, const float* __restrict__ bev,
    ushort_t* A_s, float (*sbuf)[16][6], float (*pbuf)[8])
{
    const int tid  = threadIdx.x;
    const int w    = tid >> 6;      // wave 0..7
    const int lane = tid & 63;
    const int q    = lane >> 4;     // quad 0..3
    const int c16  = lane & 15;
    const int nb   = w * 64;        // wave's 64-column base

    f32x4 acc[3][4];
#pragma unroll
    for (int m = 0; m < 3; m++)
#pragma unroll
        for (int j = 0; j < 4; j++) acc[m][j] = (f32x4){0.f, 0.f, 0.f, 0.f};

    const int koff = q * 8;
    const ushort_t* bp = Wt + (nb + c16) * KPAD + koff;
    const ushort_t* ap = A_s + c16 * SROW + koff;

    // FULL UNROLL: KPAD is constexpr -> all ds_read/global_load offsets become
    // immediates (single base per stream), killing per-kstep address VALU.
#pragma unroll
    for (int ks = 0; ks < KPAD / 32; ks++) {
        bf16x8 af[3], bf[4];
#pragma unroll
        for (int m = 0; m < 3; m++)
            af[m] = *(const bf16x8*)(ap + m * 16 * SROW + ks * 32);
#pragma unroll
        for (int j = 0; j < 4; j++)
            bf[j] = *(const bf16x8*)(bp + j * 16 * KPAD + ks * 32);
#pragma unroll
        for (int m = 0; m < 3; m++)
#pragma unroll
            for (int j = 0; j < 4; j++)
                acc[m][j] = __builtin_amdgcn_mfma_f32_16x16x32_bf16(af[m], bf[j], acc[m][j], 0, 0, 0);
    }

    // bias on primal rows
#pragma unroll
    for (int j = 0; j < 4; j++) {
        float bv = bb[nb + 16 * j + c16];
#pragma unroll
        for (int r = 0; r < 4; r++) acc[0][j][r] += bv;
    }

    // wave-local LN stats (6 sums per token over this wave's 64 cols)
    float st[4][6];
#pragma unroll
    for (int r = 0; r < 4; r++) {
        float s1 = 0.f, s2 = 0.f, a0 = 0.f, x0 = 0.f, a1 = 0.f, x1 = 0.f;
#pragma unroll
        for (int j = 0; j < 4; j++) {
            float p = acc[0][j][r], u0 = acc[1][j][r], u1 = acc[2][j][r];
            s1 += p; s2 += p * p;
            a0 += u0; x0 += p * u0;
            a1 += u1; x1 += p * u1;
        }
        st[r][0] = s1; st[r][1] = s2; st[r][2] = a0; st[r][3] = x0; st[r][4] = a1; st[r][5] = x1;
    }
#pragma unroll
    for (int d = 1; d <= 8; d <<= 1)
#pragma unroll
        for (int r = 0; r < 4; r++)
#pragma unroll
            for (int s = 0; s < 6; s++) st[r][s] += __shfl_xor(st[r][s], d);
    if (c16 == 0) {
#pragma unroll
        for (int r = 0; r < 4; r++)
#pragma unroll
            for (int s = 0; s < 6; s++) sbuf[w][4 * q + r][s] = st[r][s];
    }
    __syncthreads();

    // one thread per token finalizes LN params
    if (tid < TM) {
        float s[6] = {0.f, 0.f, 0.f, 0.f, 0.f, 0.f};
#pragma unroll
        for (int ww = 0; ww < 8; ww++)
#pragma unroll
            for (int k = 0; k < 6; k++) s[k] += sbuf[ww][tid][k];
        const float inv = 1.0f / 512.0f;
        float mu  = s[0] * inv;
        float var = s[1] * inv - mu * mu;
        float rs  = rsqrtf(var + EPS);
        float dm0 = s[2] * inv, dm1 = s[4] * inv;
        float c0 = rs * (s[3] * inv - mu * dm0);
        float c1 = rs * (s[5] * inv - mu * dm1);
        pbuf[tid][0] = mu; pbuf[tid][1] = rs;
        pbuf[tid][2] = dm0; pbuf[tid][3] = c0;
        pbuf[tid][4] = dm1; pbuf[tid][5] = c1;
    }
    __syncthreads();

    // epilogue: softplus(LN) + JVP, bf16 write-back
    float gv[4], bvv[4];
#pragma unroll
    for (int j = 0; j < 4; j++) {
        gv[j]  = gg[nb + 16 * j + c16];
        bvv[j] = bev[nb + 16 * j + c16];
    }
#pragma unroll
    for (int r = 0; r < 4; r++) {
        int tok = 4 * q + r;
        float4 pa = *(const float4*)&pbuf[tok][0];
        float4 pb = *(const float4*)&pbuf[tok][4];
        float mu = pa.x, rs = pa.y, dm0 = pa.z, c0 = pa.w;
        float dm1 = pb.x, c1 = pb.y;
#pragma unroll
        for (int j = 0; j < 4; j++) {
            int n = nb + 16 * j + c16;
            float p  = acc[0][j][r], u0 = acc[1][j][r], u1 = acc[2][j][r];
            float xh = (p - mu) * rs;
            float y  = fmaf(xh, gv[j], bvv[j]);
            float e  = __expf(-fabsf(y));
            float rinv = 1.0f / (1.0f + e);
            float sig  = (y >= 0.f) ? rinv : e * rinv;
            float sp   = fmaxf(y, 0.f) + __logf(1.0f + e);
            float grs  = gv[j] * rs;
            float dy0  = grs * (u0 - dm0 - xh * c0);
            float dy1  = grs * (u1 - dm1 - xh * c1);
            A_s[tok * SROW + 2 + n]        = f2bf(sp);
            A_s[(16 + tok) * SROW + 2 + n] = f2bf(sig * dy0);
            A_s[(32 + tok) * SROW + 2 + n] = f2bf(sig * dy1);
        }
    }
    __syncthreads();
}

__global__ __launch_bounds__(512, 4) void ode_mfma(
    const float* __restrict__ t, const float* __restrict__ z, const float* __restrict__ cond,
    const ushort_t* __restrict__ Wt0, const ushort_t* __restrict__ Wt1, const ushort_t* __restrict__ Wt2,
    const float* __restrict__ b0, const float* __restrict__ g0, const float* __restrict__ be0,
    const float* __restrict__ b1, const float* __restrict__ g1, const float* __restrict__ be1,
    const float* __restrict__ b2, const float* __restrict__ g2, const float* __restrict__ be2,
    const float* __restrict__ W3, const float* __restrict__ b3,
    float* __restrict__ out)
{
    __shared__ ushort_t A_s[48 * SROW];       // rows 0..15 primal x, 16..31 u0, 32..47 u1
    __shared__ float sbuf[8][16][6];
    __shared__ float pbuf[16][8];

    const int tid = threadIdx.x;

    // ---------------- init A ----------------
    {   uint_t* A32 = (uint_t*)A_s;
        for (int i = tid; i < 48 * SROW / 2; i += 512) A32[i] = 0u;
    }
    __syncthreads();
    const float te = t[0];
    if (tid < TM) {
        int tok = tid;
        int gm  = blockIdx.x * TM + tok;
        int si  = gm & 63;
        float pos = (float)(si + 1) * (1.0f / 64.0f);
        A_s[tok * SROW + 0] = f2bf(te);
        A_s[tok * SROW + 1] = f2bf(pos);
        A_s[tok * SROW + 2] = f2bf(z[gm * 2 + 0]);
        A_s[tok * SROW + 3] = f2bf(z[gm * 2 + 1]);
        A_s[(16 + tok) * SROW + 2] = 0x3F80;   // u0 = e0 (bf16 1.0)
        A_s[(32 + tok) * SROW + 3] = 0x3F80;   // u1 = e1
    }
    {   // all 16 tokens of a block share one batch row (16 | 64)
        int bi = (blockIdx.x * TM) >> 6;
        for (int i = tid; i < TM * 128; i += 512) {
            int tok = i >> 7, c = i & 127;
            A_s[tok * SROW + 4 + c] = f2bf(cond[bi * 128 + c]);
        }
    }
    __syncthreads();

    do_layer<K0P>(Wt0, b0, g0, be0, A_s, sbuf, pbuf);
    do_layer<KHP>(Wt1, b1, g1, be1, A_s, sbuf, pbuf);
    do_layer<KHP>(Wt2, b2, g2, be2, A_s, sbuf, pbuf);

    // ---------------- layer 3: Kin=514 -> 2 outputs + divergence ----------------
    {
        int tok = tid >> 5;       // 0..15
        int l32 = tid & 31;
        int gm  = blockIdx.x * TM + tok;
        const float2* W3v = (const float2*)W3;
        float a0 = 0.f, a1 = 0.f, d0 = 0.f, d1 = 0.f;
        for (int k = l32; k < 514; k += 32) {
            float2 wv = W3v[k];
            float ax  = bf2f(A_s[tok * SROW + k]);
            float au0 = bf2f(A_s[(16 + tok) * SROW + k]);
            float au1 = bf2f(A_s[(32 + tok) * SROW + k]);
            a0 = fmaf(ax, wv.x, a0);
            a1 = fmaf(ax, wv.y, a1);
            d0 = fmaf(au0, wv.x, d0);
            d1 = fmaf(au1, wv.y, d1);
        }
#pragma unroll
        for (int d = 1; d <= 16; d <<= 1) {
            a0 += __shfl_xor(a0, d); a1 += __shfl_xor(a1, d);
            d0 += __shfl_xor(d0, d); d1 += __shfl_xor(d1, d);
        }
        if (l32 == 0) {
            out[gm * 2 + 0]    = a0 + b3[0];
            out[gm * 2 + 1]    = a1 + b3[1];
            out[NTOK * 2 + gm] = -(d0 + d1);
        }
    }
}

extern "C" void kernel_launch(void* const* d_in, const int* in_sizes, int n_in,
                              void* d_out, int out_size, void* d_ws, size_t ws_size,
                              hipStream_t stream) {
    const float* t    = (const float*)d_in[0];
    const float* z    = (const float*)d_in[1];
    const float* cond = (const float*)d_in[2];
    const float* W0   = (const float*)d_in[3];
    const float* b0   = (const float*)d_in[4];
    const float* g0   = (const float*)d_in[5];
    const float* be0  = (const float*)d_in[6];
    const float* W1   = (const float*)d_in[7];
    const float* b1   = (const float*)d_in[8];
    const float* g1   = (const float*)d_in[9];
    const float* be1  = (const float*)d_in[10];
    const float* W2   = (const float*)d_in[11];
    const float* b2   = (const float*)d_in[12];
    const float* g2   = (const float*)d_in[13];
    const float* be2  = (const float*)d_in[14];
    const float* W3   = (const float*)d_in[15];
    const float* b3   = (const float*)d_in[16];
    float* out = (float*)d_out;

    ushort_t* Wt0 = (ushort_t*)d_ws;                    // 512*160
    ushort_t* Wt1 = Wt0 + 512 * K0P;                    // 512*544
    ushort_t* Wt2 = Wt1 + 512 * KHP;                    // 512*544

    hipLaunchKernelGGL(prep_w, dim3(512), dim3(256), 0, stream, W0, Wt0, 132, K0P);
    hipLaunchKernelGGL(prep_w, dim3(512), dim3(256), 0, stream, W1, Wt1, 514, KHP);
    hipLaunchKernelGGL(prep_w, dim3(512), dim3(256), 0, stream, W2, Wt2, 514, KHP);

    hipLaunchKernelGGL(ode_mfma, dim3(NTOK / TM), dim3(512), 0, stream,
                       t, z, cond, Wt0, Wt1, Wt2,
                       b0, g0, be0, b1, g1, be1, b2, g2, be2, W3, b3, out);
}